// Round 1
// baseline (735.294 us; speedup 1.0000x reference)
//
#include <hip/hip_runtime.h>
#include <hip/hip_bf16.h>

typedef __bf16 bf16x8 __attribute__((ext_vector_type(8)));
typedef float f32x4 __attribute__((ext_vector_type(4)));
typedef unsigned short u16;
typedef unsigned short u16x8 __attribute__((ext_vector_type(8)));

__device__ __forceinline__ u16 f2b(float f) {
  union { float f; unsigned u; } v; v.f = f;
  unsigned r = v.u + 0x7fffu + ((v.u >> 16) & 1u);
  return (u16)(r >> 16);
}

// ---------------- cast 4 weight matrices (512x512 each) to bf16 ----------------
__global__ void cast4_k(const float* __restrict__ a0, const float* __restrict__ a1,
                        const float* __restrict__ a2, const float* __restrict__ a3,
                        u16* __restrict__ o) {
  const float* src = blockIdx.y == 0 ? a0 : blockIdx.y == 1 ? a1 : blockIdx.y == 2 ? a2 : a3;
  int i = blockIdx.x * 256 + threadIdx.x;
  o[(size_t)blockIdx.y * 262144 + i] = f2b(src[i]);
}

// ---------------- GroupNorm: x (b,c,hw) fp32 -> xn_t (b,hw,c) bf16 ----------------
// grid (32 groups, 4 batch), 256 threads
__global__ void gn_k(const float* __restrict__ x, const float* __restrict__ g_,
                     const float* __restrict__ b_, u16* __restrict__ xnt) {
  const int g = blockIdx.x, b = blockIdx.y;
  const float* xb = x + ((size_t)b * 512 + g * 16) * 4096;
  u16* ob = xnt + (size_t)b * 4096 * 512 + g * 16;
  const float4* x4 = (const float4*)xb;
  float s = 0.f, ss = 0.f;
  for (int i = threadIdx.x; i < 16384; i += 256) {
    float4 v = x4[i];
    s += v.x + v.y + v.z + v.w;
    ss += v.x * v.x + v.y * v.y + v.z * v.z + v.w * v.w;
  }
  #pragma unroll
  for (int o = 32; o; o >>= 1) { s += __shfl_down(s, o); ss += __shfl_down(ss, o); }
  __shared__ float rs[4], rss[4];
  if ((threadIdx.x & 63) == 0) { rs[threadIdx.x >> 6] = s; rss[threadIdx.x >> 6] = ss; }
  __syncthreads();
  s = rs[0] + rs[1] + rs[2] + rs[3];
  ss = rss[0] + rss[1] + rss[2] + rss[3];
  const float mean = s * (1.f / 65536.f);
  const float rstd = rsqrtf(ss * (1.f / 65536.f) - mean * mean + 1e-6f);
  __shared__ float tile[16 * 257];
  const int cc_w = threadIdx.x & 15;
  const float gam = g_[g * 16 + cc_w] * rstd;
  const float bet = b_[g * 16 + cc_w] - mean * gam;
  for (int s0 = 0; s0 < 4096; s0 += 256) {
    __syncthreads();
    #pragma unroll
    for (int cc = 0; cc < 16; ++cc)
      tile[cc * 257 + threadIdx.x] = xb[(size_t)cc * 4096 + s0 + threadIdx.x];
    __syncthreads();
    #pragma unroll
    for (int it = 0; it < 16; ++it) {
      int sl = it * 16 + (threadIdx.x >> 4);
      float v = tile[cc_w * 257 + sl] * gam + bet;
      ob[(size_t)(s0 + sl) * 512 + cc_w] = f2b(v);
    }
  }
}

// ---------------- row softmax: S (4096x4096 fp32) -> P bf16 ----------------
// one block (256 thr) per row
__global__ void softmax_k(const float* __restrict__ S, u16* __restrict__ P) {
  const size_t ro = (size_t)blockIdx.x * 4096;
  const float4* rv = (const float4*)(S + ro);
  const int tid = threadIdx.x;
  float4 v[4];
  #pragma unroll
  for (int t = 0; t < 4; ++t) v[t] = rv[t * 256 + tid];
  float mx = -1e30f;
  #pragma unroll
  for (int t = 0; t < 4; ++t)
    mx = fmaxf(fmaxf(fmaxf(mx, v[t].x), fmaxf(v[t].y, v[t].z)), v[t].w);
  #pragma unroll
  for (int o = 32; o; o >>= 1) mx = fmaxf(mx, __shfl_down(mx, o));
  __shared__ float rm[4], rsu[4];
  if ((tid & 63) == 0) rm[tid >> 6] = mx;
  __syncthreads();
  mx = fmaxf(fmaxf(rm[0], rm[1]), fmaxf(rm[2], rm[3]));
  float sum = 0.f;
  #pragma unroll
  for (int t = 0; t < 4; ++t) {
    v[t].x = __expf(v[t].x - mx); v[t].y = __expf(v[t].y - mx);
    v[t].z = __expf(v[t].z - mx); v[t].w = __expf(v[t].w - mx);
    sum += v[t].x + v[t].y + v[t].z + v[t].w;
  }
  #pragma unroll
  for (int o = 32; o; o >>= 1) sum += __shfl_down(sum, o);
  if ((tid & 63) == 0) rsu[tid >> 6] = sum;
  __syncthreads();
  const float rinv = 1.f / (rsu[0] + rsu[1] + rsu[2] + rsu[3]);
  #pragma unroll
  for (int t = 0; t < 4; ++t) {
    ushort4 o4;
    o4.x = f2b(v[t].x * rinv); o4.y = f2b(v[t].y * rinv);
    o4.z = f2b(v[t].z * rinv); o4.w = f2b(v[t].w * rinv);
    ((ushort4*)(P + ro))[t * 256 + tid] = o4;
  }
}

// ---------------- unified bf16 MFMA GEMM ----------------
// D[m][n] = sum_k A_t[m][k] * B_t[n][k]   (both operands K-major)
// MODE 2: C fp32 = D*scale (m-major)              [scores]
// MODE 3: C fp32 = D + bias[m] + resid (m-major)  [final proj + residual]
// MODE 4: C bf16 = D (m-major)                    [PV]
// MODE 5: QKV combined: z = proj*4+batch; q,k -> n-major bf16 +bias; v -> m-major bf16 +bias
template<int MODE, int BM, int BN>
__global__ void gemm_k(const u16* __restrict__ A, int lda, long long sAz,
                       const u16* __restrict__ B, int ldb, long long sBz,
                       void* __restrict__ Cp_, int ldc, long long sCz,
                       int K,
                       const float* __restrict__ bias,
                       const float* __restrict__ resid, long long sRz,
                       float scale,
                       u16* __restrict__ Cq, u16* __restrict__ Ck, u16* __restrict__ Cvv,
                       const float* __restrict__ bq, const float* __restrict__ bk,
                       const float* __restrict__ bvp) {
  constexpr int LK = 72;  // 64 + 8 pad (16B) -> 2-way-max LDS conflicts (free)
  __shared__ u16 As[BM * LK];
  __shared__ u16 Bs[BN * LK];
  const int tid = threadIdx.x;
  const int m0 = blockIdx.y * BM;
  const int n0 = blockIdx.x * BN;

  const u16* Ab;
  const u16* Bb;
  if constexpr (MODE == 5) {
    int proj = blockIdx.z >> 2, b = blockIdx.z & 3;
    Ab = A + (size_t)proj * 512 * 512;
    Bb = B + (size_t)b * 4096 * 512;
  } else {
    Ab = A + (size_t)blockIdx.z * sAz;
    Bb = B + (size_t)blockIdx.z * sBz;
  }

  constexpr int FM = BM / 32, FN = BN / 32;
  f32x4 acc[FM][FN];
  #pragma unroll
  for (int i = 0; i < FM; ++i)
    #pragma unroll
    for (int j = 0; j < FN; ++j)
      acc[i][j] = (f32x4){0.f, 0.f, 0.f, 0.f};

  const int srow = tid >> 3;
  const int scol = (tid & 7) * 8;
  const int wid = tid >> 6;
  const int lane = tid & 63;
  const int wm = (wid >> 1) * (BM / 2);
  const int wn = (wid & 1) * (BN / 2);
  const int l15 = lane & 15;
  const int lk8 = (lane >> 4) * 8;

  for (int k0 = 0; k0 < K; k0 += 64) {
    #pragma unroll
    for (int r = 0; r < BM / 32; ++r) {
      int rr = srow + r * 32;
      u16x8 v = *(const u16x8*)(Ab + (size_t)(m0 + rr) * lda + k0 + scol);
      *(u16x8*)&As[rr * LK + scol] = v;
    }
    #pragma unroll
    for (int r = 0; r < BN / 32; ++r) {
      int rr = srow + r * 32;
      u16x8 v = *(const u16x8*)(Bb + (size_t)(n0 + rr) * ldb + k0 + scol);
      *(u16x8*)&Bs[rr * LK + scol] = v;
    }
    __syncthreads();
    #pragma unroll
    for (int kk = 0; kk < 64; kk += 32) {
      bf16x8 af[FM], bfr[FN];
      #pragma unroll
      for (int i = 0; i < FM; ++i)
        af[i] = *(const bf16x8*)&As[(wm + i * 16 + l15) * LK + kk + lk8];
      #pragma unroll
      for (int j = 0; j < FN; ++j)
        bfr[j] = *(const bf16x8*)&Bs[(wn + j * 16 + l15) * LK + kk + lk8];
      #pragma unroll
      for (int i = 0; i < FM; ++i)
        #pragma unroll
        for (int j = 0; j < FN; ++j)
          acc[i][j] = __builtin_amdgcn_mfma_f32_16x16x32_bf16(af[i], bfr[j], acc[i][j], 0, 0, 0);
    }
    __syncthreads();
  }

  const int lq4 = (lane >> 4) * 4;
  if constexpr (MODE == 5) {
    int proj = blockIdx.z >> 2, b = blockIdx.z & 3;
    const float* bs = proj == 0 ? bq : (proj == 1 ? bk : bvp);
    if (proj < 2) {
      u16* C = (proj == 0 ? Cq : Ck) + (size_t)b * 4096 * 512;
      #pragma unroll
      for (int i = 0; i < FM; ++i) {
        int mb = m0 + wm + i * 16 + lq4;
        float b0 = bs[mb], b1 = bs[mb + 1], b2 = bs[mb + 2], b3 = bs[mb + 3];
        #pragma unroll
        for (int j = 0; j < FN; ++j) {
          int n = n0 + wn + j * 16 + l15;
          ushort4 o4;
          o4.x = f2b(acc[i][j][0] + b0); o4.y = f2b(acc[i][j][1] + b1);
          o4.z = f2b(acc[i][j][2] + b2); o4.w = f2b(acc[i][j][3] + b3);
          *(ushort4*)(C + (size_t)n * 512 + mb) = o4;  // n-major (q_t / k_t)
        }
      }
    } else {
      u16* C = Cvv + (size_t)b * 512 * 4096;
      #pragma unroll
      for (int i = 0; i < FM; ++i) {
        int mb = m0 + wm + i * 16 + lq4;
        #pragma unroll
        for (int j = 0; j < FN; ++j) {
          int n = n0 + wn + j * 16 + l15;
          #pragma unroll
          for (int r = 0; r < 4; ++r)
            C[(size_t)(mb + r) * 4096 + n] = f2b(acc[i][j][r] + bs[mb + r]);  // m-major (v)
        }
      }
    }
    return;
  }

  const long long zz = blockIdx.z;
  #pragma unroll
  for (int i = 0; i < FM; ++i) {
    int mb = m0 + wm + i * 16 + lq4;
    #pragma unroll
    for (int j = 0; j < FN; ++j) {
      int n = n0 + wn + j * 16 + l15;
      if constexpr (MODE == 2) {
        float* C = (float*)Cp_ + zz * sCz;
        #pragma unroll
        for (int r = 0; r < 4; ++r)
          C[(size_t)(mb + r) * ldc + n] = acc[i][j][r] * scale;
      } else if constexpr (MODE == 3) {
        float* C = (float*)Cp_ + zz * sCz;
        const float* R = resid + zz * sRz;
        #pragma unroll
        for (int r = 0; r < 4; ++r)
          C[(size_t)(mb + r) * ldc + n] = acc[i][j][r] + bias[mb + r] + R[(size_t)(mb + r) * ldc + n];
      } else if constexpr (MODE == 4) {
        u16* C = (u16*)Cp_ + zz * sCz;
        #pragma unroll
        for (int r = 0; r < 4; ++r)
          C[(size_t)(mb + r) * ldc + n] = f2b(acc[i][j][r]);
      }
    }
  }
}

extern "C" void kernel_launch(void* const* d_in, const int* in_sizes, int n_in,
                              void* d_out, int out_size, void* d_ws, size_t ws_size,
                              hipStream_t stream) {
  const float* x     = (const float*)d_in[0];
  const float* gamma = (const float*)d_in[1];
  const float* beta  = (const float*)d_in[2];
  const float* wq    = (const float*)d_in[3];
  const float* bq    = (const float*)d_in[4];
  const float* wk    = (const float*)d_in[5];
  const float* bk    = (const float*)d_in[6];
  const float* wv    = (const float*)d_in[7];
  const float* bv    = (const float*)d_in[8];
  const float* wo    = (const float*)d_in[9];
  const float* bo    = (const float*)d_in[10];
  float* out = (float*)d_out;

  const size_t BHW = (size_t)4096 * 512;  // elems per batch per tensor
  u16* Wb  = (u16*)d_ws;                  // 4 x 512x512 bf16 (q,k,v,o)
  u16* xnt = Wb + (size_t)4 * 512 * 512;  // (b, s, c) bf16
  u16* qt  = xnt + 4 * BHW;               // (b, s, c)
  u16* kt  = qt + 4 * BHW;                // (b, s, c)
  u16* vv  = kt + 4 * BHW;                // (b, c, s)
  u16* aot = vv + 4 * BHW;                // (b, s, c)
  float* Sb = (float*)(aot + 4 * BHW);    // 4096x4096 fp32 (reused per batch)
  u16* Pb  = (u16*)(Sb + (size_t)4096 * 4096);  // 4096x4096 bf16

  const float scale = 0.044194173824159216f;  // 512^-0.5

  hipLaunchKernelGGL(cast4_k, dim3(1024, 4), dim3(256), 0, stream, wq, wk, wv, wo, Wb);
  hipLaunchKernelGGL(gn_k, dim3(32, 4), dim3(256), 0, stream, x, gamma, beta, xnt);

  // QKV: M=512 (c_out), N=4096 (s), K=512; z = proj*4 + batch
  hipLaunchKernelGGL((gemm_k<5, 128, 128>), dim3(32, 4, 12), dim3(256), 0, stream,
                     Wb, 512, 0LL, xnt, 512, 0LL, nullptr, 0, 0LL, 512,
                     nullptr, nullptr, 0LL, 0.f, qt, kt, vv, bq, bk, bv);

  for (int b = 0; b < 4; ++b) {
    const u16* qb = qt + (size_t)b * BHW;
    const u16* kb = kt + (size_t)b * BHW;
    const u16* vb = vv + (size_t)b * BHW;
    u16* aob = aot + (size_t)b * BHW;
    // S[i][j] = sum_c q_t[i][c]*k_t[j][c] * scale ; M=N=4096, K=512
    hipLaunchKernelGGL((gemm_k<2, 128, 128>), dim3(32, 32, 1), dim3(256), 0, stream,
                       qb, 512, 0LL, kb, 512, 0LL, Sb, 4096, 0LL, 512,
                       nullptr, nullptr, 0LL, scale,
                       nullptr, nullptr, nullptr, nullptr, nullptr, nullptr);
    hipLaunchKernelGGL(softmax_k, dim3(4096), dim3(256), 0, stream, Sb, Pb);
    // ao_t[i][c] = sum_j P[i][j]*v[c][j] ; M=4096 (i), N=512 (c), K=4096
    hipLaunchKernelGGL((gemm_k<4, 128, 64>), dim3(8, 32, 1), dim3(256), 0, stream,
                       Pb, 4096, 0LL, vb, 4096, 0LL, aob, 512, 0LL, 4096,
                       nullptr, nullptr, 0LL, 0.f,
                       nullptr, nullptr, nullptr, nullptr, nullptr, nullptr);
  }

  // final: y[co][s] = sum_ci Wo[co][ci]*ao_t[s][ci] + bo[co] + x ; M=512, N=4096, K=512
  hipLaunchKernelGGL((gemm_k<3, 128, 128>), dim3(32, 4, 4), dim3(256), 0, stream,
                     Wb + (size_t)3 * 512 * 512, 512, 0LL, aot, 512, (long long)BHW,
                     out, 4096, (long long)BHW, 512,
                     bo, x, (long long)BHW, 0.f,
                     nullptr, nullptr, nullptr, nullptr, nullptr, nullptr);
}

// Round 2
// 502.709 us; speedup vs baseline: 1.4627x; 1.4627x over previous
//
#include <hip/hip_runtime.h>

typedef _Float16 f16x8 __attribute__((ext_vector_type(8)));
typedef float f32x4 __attribute__((ext_vector_type(4)));
typedef unsigned short u16;
typedef unsigned short u16x8 __attribute__((ext_vector_type(8)));

__device__ __forceinline__ u16 f2h(float f) {
  union { _Float16 h; u16 u; } v; v.h = (_Float16)f; return v.u;
}
__device__ __forceinline__ float h2f(u16 u) {
  union { _Float16 h; u16 u; } v; v.u = u; return (float)v.h;
}

// ---------------- cast 4 weight matrices (512x512 each) to fp16 ----------------
__global__ void cast4_k(const float* __restrict__ a0, const float* __restrict__ a1,
                        const float* __restrict__ a2, const float* __restrict__ a3,
                        u16* __restrict__ o) {
  const float* src = blockIdx.y == 0 ? a0 : blockIdx.y == 1 ? a1 : blockIdx.y == 2 ? a2 : a3;
  int i = blockIdx.x * 256 + threadIdx.x;
  o[(size_t)blockIdx.y * 262144 + i] = f2h(src[i]);
}

// ---------------- GroupNorm: x (b,c,hw) fp32 -> xn_t (b,hw,c) fp16 ----------------
__global__ void gn_k(const float* __restrict__ x, const float* __restrict__ g_,
                     const float* __restrict__ b_, u16* __restrict__ xnt) {
  const int g = blockIdx.x, b = blockIdx.y;
  const float* xb = x + ((size_t)b * 512 + g * 16) * 4096;
  u16* ob = xnt + (size_t)b * 4096 * 512 + g * 16;
  const float4* x4 = (const float4*)xb;
  float s = 0.f, ss = 0.f;
  for (int i = threadIdx.x; i < 16384; i += 256) {
    float4 v = x4[i];
    s += v.x + v.y + v.z + v.w;
    ss += v.x * v.x + v.y * v.y + v.z * v.z + v.w * v.w;
  }
  #pragma unroll
  for (int o = 32; o; o >>= 1) { s += __shfl_down(s, o); ss += __shfl_down(ss, o); }
  __shared__ float rs[4], rss[4];
  if ((threadIdx.x & 63) == 0) { rs[threadIdx.x >> 6] = s; rss[threadIdx.x >> 6] = ss; }
  __syncthreads();
  s = rs[0] + rs[1] + rs[2] + rs[3];
  ss = rss[0] + rss[1] + rss[2] + rss[3];
  const float mean = s * (1.f / 65536.f);
  const float rstd = rsqrtf(ss * (1.f / 65536.f) - mean * mean + 1e-6f);
  __shared__ float tile[16 * 257];
  const int cc_w = threadIdx.x & 15;
  const float gam = g_[g * 16 + cc_w] * rstd;
  const float bet = b_[g * 16 + cc_w] - mean * gam;
  for (int s0 = 0; s0 < 4096; s0 += 256) {
    __syncthreads();
    #pragma unroll
    for (int cc = 0; cc < 16; ++cc)
      tile[cc * 257 + threadIdx.x] = xb[(size_t)cc * 4096 + s0 + threadIdx.x];
    __syncthreads();
    #pragma unroll
    for (int it = 0; it < 16; ++it) {
      int sl = it * 16 + (threadIdx.x >> 4);
      float v = tile[cc_w * 257 + sl] * gam + bet;
      ob[(size_t)(s0 + sl) * 512 + cc_w] = f2h(v);
    }
  }
}

// ---------------- row softmax, in-place on S fp16; grid (4096, batch) ----------------
__global__ void softmax_k(u16* __restrict__ S) {
  const size_t ro = ((size_t)blockIdx.y * 4096 + blockIdx.x) * 4096;
  u16x8* rv = (u16x8*)(S + ro);
  const int tid = threadIdx.x;
  u16x8 h[2];
  h[0] = rv[tid];
  h[1] = rv[256 + tid];
  float v[16];
  #pragma unroll
  for (int t = 0; t < 2; ++t)
    #pragma unroll
    for (int j = 0; j < 8; ++j) v[t * 8 + j] = h2f(h[t][j]);
  float mx = -1e30f;
  #pragma unroll
  for (int i = 0; i < 16; ++i) mx = fmaxf(mx, v[i]);
  #pragma unroll
  for (int o = 32; o; o >>= 1) mx = fmaxf(mx, __shfl_down(mx, o));
  __shared__ float rm[4], rsu[4];
  if ((tid & 63) == 0) rm[tid >> 6] = mx;
  __syncthreads();
  mx = fmaxf(fmaxf(rm[0], rm[1]), fmaxf(rm[2], rm[3]));
  float sum = 0.f;
  #pragma unroll
  for (int i = 0; i < 16; ++i) { v[i] = __expf(v[i] - mx); sum += v[i]; }
  #pragma unroll
  for (int o = 32; o; o >>= 1) sum += __shfl_down(sum, o);
  if ((tid & 63) == 0) rsu[tid >> 6] = sum;
  __syncthreads();
  const float rinv = 1.f / (rsu[0] + rsu[1] + rsu[2] + rsu[3]);
  #pragma unroll
  for (int t = 0; t < 2; ++t) {
    u16x8 o8;
    #pragma unroll
    for (int j = 0; j < 8; ++j) o8[j] = f2h(v[t * 8 + j] * rinv);
    rv[t * 256 + tid] = o8;
  }
}

// ---------------- unified fp16 MFMA GEMM ----------------
// D[m][n] = sum_k A_t[m][k] * B_t[n][k]   (both operands K-major)
// MODE 2: C fp16 = D*scale (m-major)              [scores]
// MODE 3: C fp32 = D + bias[m] + resid (m-major)  [final proj + residual]
// MODE 4: C fp16 = D (m-major)                    [PV]
// MODE 5: QKV: z = proj*4+batch; q,k -> n-major fp16 +bias; v -> m-major fp16 +bias
template<int MODE, int BM, int BN>
__global__ void gemm_k(const u16* __restrict__ A, int lda, long long sAz,
                       const u16* __restrict__ B, int ldb, long long sBz,
                       void* __restrict__ Cp_, int ldc, long long sCz,
                       int K,
                       const float* __restrict__ bias,
                       const float* __restrict__ resid, long long sRz,
                       float scale,
                       u16* __restrict__ Cq, u16* __restrict__ Ck, u16* __restrict__ Cvv,
                       const float* __restrict__ bq, const float* __restrict__ bk,
                       const float* __restrict__ bvp) {
  // chunked XCD swizzle (T1): block lin -> work (lin%8)*(nwg/8)+lin/8 so
  // consecutive work items (sharing A/B panels) stay on one XCD's L2.
  const unsigned gx = gridDim.x, gy = gridDim.y;
  const unsigned lin = (blockIdx.z * gy + blockIdx.y) * gx + blockIdx.x;
  const unsigned nwg = gx * gy * gridDim.z;
  const unsigned swz = (lin & 7) * (nwg >> 3) + (lin >> 3);
  const unsigned bx = swz % gx;
  const unsigned rem = swz / gx;
  const unsigned by = rem % gy;
  const unsigned bz = rem / gy;

  constexpr int LK = 72;  // 64 + 8 pad (16B) -> 2-way-max LDS conflicts (free)
  __shared__ u16 As[BM * LK];
  __shared__ u16 Bs[BN * LK];
  const int tid = threadIdx.x;
  const int m0 = by * BM;
  const int n0 = bx * BN;

  const u16* Ab;
  const u16* Bb;
  if constexpr (MODE == 5) {
    int proj = bz >> 2, b = bz & 3;
    Ab = A + (size_t)proj * 512 * 512;
    Bb = B + (size_t)b * 4096 * 512;
  } else {
    Ab = A + (size_t)bz * sAz;
    Bb = B + (size_t)bz * sBz;
  }

  constexpr int FM = BM / 32, FN = BN / 32;
  f32x4 acc[FM][FN];
  #pragma unroll
  for (int i = 0; i < FM; ++i)
    #pragma unroll
    for (int j = 0; j < FN; ++j)
      acc[i][j] = (f32x4){0.f, 0.f, 0.f, 0.f};

  const int srow = tid >> 3;
  const int scol = (tid & 7) * 8;
  const int wid = tid >> 6;
  const int lane = tid & 63;
  const int wm = (wid >> 1) * (BM / 2);
  const int wn = (wid & 1) * (BN / 2);
  const int l15 = lane & 15;
  const int lk8 = (lane >> 4) * 8;

  for (int k0 = 0; k0 < K; k0 += 64) {
    #pragma unroll
    for (int r = 0; r < BM / 32; ++r) {
      int rr = srow + r * 32;
      u16x8 v = *(const u16x8*)(Ab + (size_t)(m0 + rr) * lda + k0 + scol);
      *(u16x8*)&As[rr * LK + scol] = v;
    }
    #pragma unroll
    for (int r = 0; r < BN / 32; ++r) {
      int rr = srow + r * 32;
      u16x8 v = *(const u16x8*)(Bb + (size_t)(n0 + rr) * ldb + k0 + scol);
      *(u16x8*)&Bs[rr * LK + scol] = v;
    }
    __syncthreads();
    #pragma unroll
    for (int kk = 0; kk < 64; kk += 32) {
      f16x8 af[FM], bfr[FN];
      #pragma unroll
      for (int i = 0; i < FM; ++i)
        af[i] = *(const f16x8*)&As[(wm + i * 16 + l15) * LK + kk + lk8];
      #pragma unroll
      for (int j = 0; j < FN; ++j)
        bfr[j] = *(const f16x8*)&Bs[(wn + j * 16 + l15) * LK + kk + lk8];
      #pragma unroll
      for (int i = 0; i < FM; ++i)
        #pragma unroll
        for (int j = 0; j < FN; ++j)
          acc[i][j] = __builtin_amdgcn_mfma_f32_16x16x32_f16(af[i], bfr[j], acc[i][j], 0, 0, 0);
    }
    __syncthreads();
  }

  const int lq4 = (lane >> 4) * 4;
  if constexpr (MODE == 5) {
    int proj = bz >> 2, b = bz & 3;
    const float* bs = proj == 0 ? bq : (proj == 1 ? bk : bvp);
    if (proj < 2) {
      u16* C = (proj == 0 ? Cq : Ck) + (size_t)b * 4096 * 512;
      #pragma unroll
      for (int i = 0; i < FM; ++i) {
        int mb = m0 + wm + i * 16 + lq4;
        float b0 = bs[mb], b1 = bs[mb + 1], b2 = bs[mb + 2], b3 = bs[mb + 3];
        #pragma unroll
        for (int j = 0; j < FN; ++j) {
          int n = n0 + wn + j * 16 + l15;
          ushort4 o4;
          o4.x = f2h(acc[i][j][0] + b0); o4.y = f2h(acc[i][j][1] + b1);
          o4.z = f2h(acc[i][j][2] + b2); o4.w = f2h(acc[i][j][3] + b3);
          *(ushort4*)(C + (size_t)n * 512 + mb) = o4;  // n-major (q_t / k_t)
        }
      }
    } else {
      u16* C = Cvv + (size_t)b * 512 * 4096;
      #pragma unroll
      for (int i = 0; i < FM; ++i) {
        int mb = m0 + wm + i * 16 + lq4;
        #pragma unroll
        for (int j = 0; j < FN; ++j) {
          int n = n0 + wn + j * 16 + l15;
          #pragma unroll
          for (int r = 0; r < 4; ++r)
            C[(size_t)(mb + r) * 4096 + n] = f2h(acc[i][j][r] + bs[mb + r]);  // m-major (v)
        }
      }
    }
    return;
  }

  const long long zz = bz;
  #pragma unroll
  for (int i = 0; i < FM; ++i) {
    int mb = m0 + wm + i * 16 + lq4;
    #pragma unroll
    for (int j = 0; j < FN; ++j) {
      int n = n0 + wn + j * 16 + l15;
      if constexpr (MODE == 2) {
        u16* C = (u16*)Cp_ + zz * sCz;
        #pragma unroll
        for (int r = 0; r < 4; ++r)
          C[(size_t)(mb + r) * ldc + n] = f2h(acc[i][j][r] * scale);
      } else if constexpr (MODE == 3) {
        float* C = (float*)Cp_ + zz * sCz;
        const float* R = resid + zz * sRz;
        #pragma unroll
        for (int r = 0; r < 4; ++r)
          C[(size_t)(mb + r) * ldc + n] = acc[i][j][r] + bias[mb + r] + R[(size_t)(mb + r) * ldc + n];
      } else if constexpr (MODE == 4) {
        u16* C = (u16*)Cp_ + zz * sCz;
        #pragma unroll
        for (int r = 0; r < 4; ++r)
          C[(size_t)(mb + r) * ldc + n] = f2h(acc[i][j][r]);
      }
    }
  }
}

extern "C" void kernel_launch(void* const* d_in, const int* in_sizes, int n_in,
                              void* d_out, int out_size, void* d_ws, size_t ws_size,
                              hipStream_t stream) {
  const float* x     = (const float*)d_in[0];
  const float* gamma = (const float*)d_in[1];
  const float* beta  = (const float*)d_in[2];
  const float* wq    = (const float*)d_in[3];
  const float* bq    = (const float*)d_in[4];
  const float* wk    = (const float*)d_in[5];
  const float* bk    = (const float*)d_in[6];
  const float* wv    = (const float*)d_in[7];
  const float* bv    = (const float*)d_in[8];
  const float* wo    = (const float*)d_in[9];
  const float* bo    = (const float*)d_in[10];
  float* out = (float*)d_out;

  const size_t BHW = (size_t)4096 * 512;       // elems per batch per tensor
  const long long SS = 16777216LL;             // 4096*4096, per-batch S elems
  u16* Wh  = (u16*)d_ws;                       // 4 x 512x512 fp16
  u16* xnt = Wh + (size_t)4 * 512 * 512;       // (b, s, c) fp16 — reused as aot later
  u16* qt  = xnt + 4 * BHW;                    // (b, s, c)
  u16* kt  = qt + 4 * BHW;                     // (b, s, c)
  u16* vv  = kt + 4 * BHW;                     // (b, c, s)
  u16* Sb  = vv + 4 * BHW;                     // (b, 4096, 4096) fp16, softmaxed in-place
  u16* aot = xnt;                              // alias: xnt is dead after QKV

  const float scale = 0.044194173824159216f;   // 512^-0.5

  hipLaunchKernelGGL(cast4_k, dim3(1024, 4), dim3(256), 0, stream, wq, wk, wv, wo, Wh);
  hipLaunchKernelGGL(gn_k, dim3(32, 4), dim3(256), 0, stream, x, gamma, beta, xnt);

  // QKV: M=512 (c_out), N=4096 (s), K=512; z = proj*4 + batch
  hipLaunchKernelGGL((gemm_k<5, 128, 128>), dim3(32, 4, 12), dim3(256), 0, stream,
                     Wh, 512, 0LL, xnt, 512, 0LL, nullptr, 0, 0LL, 512,
                     nullptr, nullptr, 0LL, 0.f, qt, kt, vv, bq, bk, bv);

  // S[b][i][j] = sum_c q_t[i][c]*k_t[j][c] * scale ; M=N=4096, K=512, z=batch
  hipLaunchKernelGGL((gemm_k<2, 128, 128>), dim3(32, 32, 4), dim3(256), 0, stream,
                     qt, 512, (long long)BHW, kt, 512, (long long)BHW, Sb, 4096, SS, 512,
                     nullptr, nullptr, 0LL, scale,
                     nullptr, nullptr, nullptr, nullptr, nullptr, nullptr);

  hipLaunchKernelGGL(softmax_k, dim3(4096, 4), dim3(256), 0, stream, Sb);

  // ao_t[b][i][c] = sum_j P[i][j]*v[c][j] ; M=4096 (i), N=512 (c), K=4096, z=batch
  hipLaunchKernelGGL((gemm_k<4, 128, 64>), dim3(8, 32, 4), dim3(256), 0, stream,
                     Sb, 4096, SS, vv, 4096, (long long)BHW, aot, 512, (long long)BHW, 4096,
                     nullptr, nullptr, 0LL, 0.f,
                     nullptr, nullptr, nullptr, nullptr, nullptr, nullptr);

  // final: y[b][co][s] = sum_ci Wo[co][ci]*ao_t[s][ci] + bo[co] + x ; M=512, N=4096, K=512
  hipLaunchKernelGGL((gemm_k<3, 128, 128>), dim3(32, 4, 4), dim3(256), 0, stream,
                     Wh + (size_t)3 * 512 * 512, 512, 0LL, aot, 512, (long long)BHW,
                     out, 4096, (long long)BHW, 512,
                     bo, x, (long long)BHW, 0.f,
                     nullptr, nullptr, nullptr, nullptr, nullptr, nullptr);
}

// Round 4
// 442.835 us; speedup vs baseline: 1.6604x; 1.1352x over previous
//
#include <hip/hip_runtime.h>

typedef _Float16 f16x8 __attribute__((ext_vector_type(8)));
typedef float f32x4 __attribute__((ext_vector_type(4)));
typedef unsigned short u16;
typedef unsigned short u16x8 __attribute__((ext_vector_type(8)));

__device__ __forceinline__ u16 f2h(float f) {
  union { _Float16 h; u16 u; } v; v.h = (_Float16)f; return v.u;
}
__device__ __forceinline__ float h2f(u16 u) {
  union { _Float16 h; u16 u; } v; v.u = u; return (float)v.h;
}

// async global -> LDS, 16 B per lane, wave-uniform LDS base (+lane*16 by HW)
__device__ __forceinline__ void gload16(const u16* g, u16* l) {
  __builtin_amdgcn_global_load_lds((const __attribute__((address_space(1))) unsigned*)g,
                                   (__attribute__((address_space(3))) unsigned*)l, 16, 0, 0);
}

// ---------------- cast 4 weight matrices (512x512 each) to fp16 ----------------
__global__ void cast4_k(const float* __restrict__ a0, const float* __restrict__ a1,
                        const float* __restrict__ a2, const float* __restrict__ a3,
                        u16* __restrict__ o) {
  const float* src = blockIdx.y == 0 ? a0 : blockIdx.y == 1 ? a1 : blockIdx.y == 2 ? a2 : a3;
  int i = blockIdx.x * 256 + threadIdx.x;
  o[(size_t)blockIdx.y * 262144 + i] = f2h(src[i]);
}

// ---------------- GroupNorm: x (b,c,hw) fp32 -> xn_t (b,hw,c) fp16 ----------------
__global__ void gn_k(const float* __restrict__ x, const float* __restrict__ g_,
                     const float* __restrict__ b_, u16* __restrict__ xnt) {
  const int g = blockIdx.x, b = blockIdx.y;
  const float* xb = x + ((size_t)b * 512 + g * 16) * 4096;
  u16* ob = xnt + (size_t)b * 4096 * 512 + g * 16;
  const float4* x4 = (const float4*)xb;
  float s = 0.f, ss = 0.f;
  for (int i = threadIdx.x; i < 16384; i += 256) {
    float4 v = x4[i];
    s += v.x + v.y + v.z + v.w;
    ss += v.x * v.x + v.y * v.y + v.z * v.z + v.w * v.w;
  }
  #pragma unroll
  for (int o = 32; o; o >>= 1) { s += __shfl_down(s, o); ss += __shfl_down(ss, o); }
  __shared__ float rs[4], rss[4];
  if ((threadIdx.x & 63) == 0) { rs[threadIdx.x >> 6] = s; rss[threadIdx.x >> 6] = ss; }
  __syncthreads();
  s = rs[0] + rs[1] + rs[2] + rs[3];
  ss = rss[0] + rss[1] + rss[2] + rss[3];
  const float mean = s * (1.f / 65536.f);
  const float rstd = rsqrtf(ss * (1.f / 65536.f) - mean * mean + 1e-6f);
  __shared__ float tile[16 * 257];
  const int cc_w = threadIdx.x & 15;
  const float gam = g_[g * 16 + cc_w] * rstd;
  const float bet = b_[g * 16 + cc_w] - mean * gam;
  for (int s0 = 0; s0 < 4096; s0 += 256) {
    __syncthreads();
    #pragma unroll
    for (int cc = 0; cc < 16; ++cc)
      tile[cc * 257 + threadIdx.x] = xb[(size_t)cc * 4096 + s0 + threadIdx.x];
    __syncthreads();
    #pragma unroll
    for (int it = 0; it < 16; ++it) {
      int sl = it * 16 + (threadIdx.x >> 4);
      float v = tile[cc_w * 257 + sl] * gam + bet;
      ob[(size_t)(s0 + sl) * 512 + cc_w] = f2h(v);
    }
  }
}

// ---------------- row softmax, in-place on S fp16; grid (4096, batch) ----------------
__global__ void softmax_k(u16* __restrict__ S) {
  const size_t ro = ((size_t)blockIdx.y * 4096 + blockIdx.x) * 4096;
  u16x8* rv = (u16x8*)(S + ro);
  const int tid = threadIdx.x;
  u16x8 h[2];
  h[0] = rv[tid];
  h[1] = rv[256 + tid];
  float v[16];
  #pragma unroll
  for (int t = 0; t < 2; ++t)
    #pragma unroll
    for (int j = 0; j < 8; ++j) v[t * 8 + j] = h2f(h[t][j]);
  float mx = -1e30f;
  #pragma unroll
  for (int i = 0; i < 16; ++i) mx = fmaxf(mx, v[i]);
  #pragma unroll
  for (int o = 32; o; o >>= 1) mx = fmaxf(mx, __shfl_down(mx, o));
  __shared__ float rm[4], rsu[4];
  if ((tid & 63) == 0) rm[tid >> 6] = mx;
  __syncthreads();
  mx = fmaxf(fmaxf(rm[0], rm[1]), fmaxf(rm[2], rm[3]));
  float sum = 0.f;
  #pragma unroll
  for (int i = 0; i < 16; ++i) { v[i] = __expf(v[i] - mx); sum += v[i]; }
  #pragma unroll
  for (int o = 32; o; o >>= 1) sum += __shfl_down(sum, o);
  if ((tid & 63) == 0) rsu[tid >> 6] = sum;
  __syncthreads();
  const float rinv = 1.f / (rsu[0] + rsu[1] + rsu[2] + rsu[3]);
  #pragma unroll
  for (int t = 0; t < 2; ++t) {
    u16x8 o8;
    #pragma unroll
    for (int j = 0; j < 8; ++j) o8[j] = f2h(v[t * 8 + j] * rinv);
    rv[t * 256 + tid] = o8;
  }
}

// ---------------- unified fp16 MFMA GEMM (m97 structure: global_load_lds) ----------------
// D[m][n] = sum_k A_t[m][k] * B_t[n][k]   (both operands K-major)
// MODE 2: C fp16 = D*scale (m-major)              [scores]
// MODE 3: C fp32 = D + bias[m] + resid (m-major)  [final proj + residual]
// MODE 4: C fp16 = D (m-major)                    [PV]
// MODE 5: QKV: z = proj*4+batch; q,k -> n-major fp16 +bias; v -> m-major fp16 +bias
template<int MODE, int BM, int BN>
__global__ void gemm_k(const u16* __restrict__ A, int lda, long long sAz,
                       const u16* __restrict__ B, int ldb, long long sBz,
                       void* __restrict__ Cp_, int ldc, long long sCz,
                       int K,
                       const float* __restrict__ bias,
                       const float* __restrict__ resid, long long sRz,
                       float scale,
                       u16* __restrict__ Cq, u16* __restrict__ Ck, u16* __restrict__ Cvv,
                       const float* __restrict__ bq, const float* __restrict__ bk,
                       const float* __restrict__ bvp) {
  // chunked XCD swizzle (T1)
  const unsigned gx = gridDim.x, gy = gridDim.y;
  const unsigned lin = (blockIdx.z * gy + blockIdx.y) * gx + blockIdx.x;
  const unsigned nwg = gx * gy * gridDim.z;
  const unsigned swz = (lin & 7) * (nwg >> 3) + (lin >> 3);
  const unsigned bx = swz % gx;
  const unsigned rem = swz / gx;
  const unsigned by = rem % gy;
  const unsigned bz = rem / gy;

  constexpr int LK = 64;  // linear — required by global_load_lds (no padding)
  __shared__ u16 As[BM * LK];
  __shared__ u16 Bs[BN * LK];
  const int tid = threadIdx.x;
  const int m0 = by * BM;
  const int n0 = bx * BN;

  const u16* Ab;
  const u16* Bb;
  if constexpr (MODE == 5) {
    int proj = bz >> 2, b = bz & 3;
    Ab = A + (size_t)proj * 512 * 512;
    Bb = B + (size_t)b * 4096 * 512;
  } else {
    Ab = A + (size_t)bz * sAz;
    Bb = B + (size_t)bz * sBz;
  }

  constexpr int FM = BM / 32, FN = BN / 32;
  f32x4 acc[FM][FN];
  #pragma unroll
  for (int i = 0; i < FM; ++i)
    #pragma unroll
    for (int j = 0; j < FN; ++j)
      acc[i][j] = (f32x4){0.f, 0.f, 0.f, 0.f};

  const int wid = tid >> 6;
  const int lane = tid & 63;
  const int wm = (wid >> 1) * (BM / 2);
  const int wn = (wid & 1) * (BN / 2);
  const int l15 = lane & 15;
  const int lk8 = (lane >> 4) * 8;
  const int lrow = lane >> 3;        // row within 8-row chunk
  const int lcol = (lane & 7) * 8;   // u16 col within 64-wide row

  constexpr int ACH = BM / 8;  // 1KB chunks in A tile (8 rows each)
  constexpr int BCH = BN / 8;

  for (int k0 = 0; k0 < K; k0 += 64) {
    // async stage: each wave owns ACH/4 + BCH/4 chunks; HW scatters lane*16B
    #pragma unroll
    for (int c = 0; c < ACH / 4; ++c) {
      int ch = wid * (ACH / 4) + c;
      gload16(Ab + (size_t)(m0 + ch * 8 + lrow) * lda + k0 + lcol, &As[ch * 512]);
    }
    #pragma unroll
    for (int c = 0; c < BCH / 4; ++c) {
      int ch = wid * (BCH / 4) + c;
      gload16(Bb + (size_t)(n0 + ch * 8 + lrow) * ldb + k0 + lcol, &Bs[ch * 512]);
    }
    __syncthreads();  // compiler drains vmcnt(0) before s_barrier
    #pragma unroll
    for (int kk = 0; kk < 64; kk += 32) {
      f16x8 af[FM], bfr[FN];
      #pragma unroll
      for (int i = 0; i < FM; ++i)
        af[i] = *(const f16x8*)&As[(wm + i * 16 + l15) * LK + kk + lk8];
      #pragma unroll
      for (int j = 0; j < FN; ++j)
        bfr[j] = *(const f16x8*)&Bs[(wn + j * 16 + l15) * LK + kk + lk8];
      #pragma unroll
      for (int i = 0; i < FM; ++i)
        #pragma unroll
        for (int j = 0; j < FN; ++j)
          acc[i][j] = __builtin_amdgcn_mfma_f32_16x16x32_f16(af[i], bfr[j], acc[i][j], 0, 0, 0);
    }
    __syncthreads();  // protect LDS for next stage (write-after-read)
  }

  const int lq4 = (lane >> 4) * 4;
  if constexpr (MODE == 5) {
    int proj = bz >> 2, b = bz & 3;
    const float* bs = proj == 0 ? bq : (proj == 1 ? bk : bvp);
    if (proj < 2) {
      u16* C = (proj == 0 ? Cq : Ck) + (size_t)b * 4096 * 512;
      #pragma unroll
      for (int i = 0; i < FM; ++i) {
        int mb = m0 + wm + i * 16 + lq4;
        float b0 = bs[mb], b1 = bs[mb + 1], b2 = bs[mb + 2], b3 = bs[mb + 3];
        #pragma unroll
        for (int j = 0; j < FN; ++j) {
          int n = n0 + wn + j * 16 + l15;
          ushort4 o4;
          o4.x = f2h(acc[i][j][0] + b0); o4.y = f2h(acc[i][j][1] + b1);
          o4.z = f2h(acc[i][j][2] + b2); o4.w = f2h(acc[i][j][3] + b3);
          *(ushort4*)(C + (size_t)n * 512 + mb) = o4;  // n-major (q_t / k_t)
        }
      }
    } else {
      u16* C = Cvv + (size_t)b * 512 * 4096;
      #pragma unroll
      for (int i = 0; i < FM; ++i) {
        int mb = m0 + wm + i * 16 + lq4;
        #pragma unroll
        for (int j = 0; j < FN; ++j) {
          int n = n0 + wn + j * 16 + l15;
          #pragma unroll
          for (int r = 0; r < 4; ++r)
            C[(size_t)(mb + r) * 4096 + n] = f2h(acc[i][j][r] + bs[mb + r]);  // m-major (v)
        }
      }
    }
    return;
  }

  const long long zz = bz;
  #pragma unroll
  for (int i = 0; i < FM; ++i) {
    int mb = m0 + wm + i * 16 + lq4;
    #pragma unroll
    for (int j = 0; j < FN; ++j) {
      int n = n0 + wn + j * 16 + l15;
      if constexpr (MODE == 2) {
        u16* C = (u16*)Cp_ + zz * sCz;
        #pragma unroll
        for (int r = 0; r < 4; ++r)
          C[(size_t)(mb + r) * ldc + n] = f2h(acc[i][j][r] * scale);
      } else if constexpr (MODE == 3) {
        float* C = (float*)Cp_ + zz * sCz;
        const float* R = resid + zz * sRz;
        #pragma unroll
        for (int r = 0; r < 4; ++r)
          C[(size_t)(mb + r) * ldc + n] = acc[i][j][r] + bias[mb + r] + R[(size_t)(mb + r) * ldc + n];
      } else if constexpr (MODE == 4) {
        u16* C = (u16*)Cp_ + zz * sCz;
        #pragma unroll
        for (int r = 0; r < 4; ++r)
          C[(size_t)(mb + r) * ldc + n] = f2h(acc[i][j][r]);
      }
    }
  }
}

extern "C" void kernel_launch(void* const* d_in, const int* in_sizes, int n_in,
                              void* d_out, int out_size, void* d_ws, size_t ws_size,
                              hipStream_t stream) {
  const float* x     = (const float*)d_in[0];
  const float* gamma = (const float*)d_in[1];
  const float* beta  = (const float*)d_in[2];
  const float* wq    = (const float*)d_in[3];
  const float* bq    = (const float*)d_in[4];
  const float* wk    = (const float*)d_in[5];
  const float* bk    = (const float*)d_in[6];
  const float* wv    = (const float*)d_in[7];
  const float* bv    = (const float*)d_in[8];
  const float* wo    = (const float*)d_in[9];
  const float* bo    = (const float*)d_in[10];
  float* out = (float*)d_out;

  const size_t BHW = (size_t)4096 * 512;       // elems per batch per tensor
  const long long SS = 16777216LL;             // 4096*4096, per-batch S elems
  u16* Wh  = (u16*)d_ws;                       // 4 x 512x512 fp16
  u16* xnt = Wh + (size_t)4 * 512 * 512;       // (b, s, c) fp16 — reused as aot later
  u16* qt  = xnt + 4 * BHW;                    // (b, s, c)
  u16* kt  = qt + 4 * BHW;                     // (b, s, c)
  u16* vv  = kt + 4 * BHW;                     // (b, c, s)
  u16* Sb  = vv + 4 * BHW;                     // (b, 4096, 4096) fp16, softmaxed in-place
  u16* aot = xnt;                              // alias: xnt is dead after QKV

  const float scale = 0.044194173824159216f;   // 512^-0.5

  hipLaunchKernelGGL(cast4_k, dim3(1024, 4), dim3(256), 0, stream, wq, wk, wv, wo, Wh);
  hipLaunchKernelGGL(gn_k, dim3(32, 4), dim3(256), 0, stream, x, gamma, beta, xnt);

  // QKV: M=512 (c_out), N=4096 (s), K=512; z = proj*4 + batch
  hipLaunchKernelGGL((gemm_k<5, 128, 128>), dim3(32, 4, 12), dim3(256), 0, stream,
                     Wh, 512, 0LL, xnt, 512, 0LL, nullptr, 0, 0LL, 512,
                     nullptr, nullptr, 0LL, 0.f, qt, kt, vv, bq, bk, bv);

  // S[b][i][j] = sum_c q_t[i][c]*k_t[j][c] * scale ; M=N=4096, K=512, z=batch
  hipLaunchKernelGGL((gemm_k<2, 128, 128>), dim3(32, 32, 4), dim3(256), 0, stream,
                     qt, 512, (long long)BHW, kt, 512, (long long)BHW, Sb, 4096, SS, 512,
                     nullptr, nullptr, 0LL, scale,
                     nullptr, nullptr, nullptr, nullptr, nullptr, nullptr);

  hipLaunchKernelGGL(softmax_k, dim3(4096, 4), dim3(256), 0, stream, Sb);

  // ao_t[b][i][c] = sum_j P[i][j]*v[c][j] ; M=4096 (i), N=512 (c), K=4096, z=batch
  hipLaunchKernelGGL((gemm_k<4, 128, 128>), dim3(4, 32, 4), dim3(256), 0, stream,
                     Sb, 4096, SS, vv, 4096, (long long)BHW, aot, 512, (long long)BHW, 4096,
                     nullptr, nullptr, 0LL, 0.f,
                     nullptr, nullptr, nullptr, nullptr, nullptr, nullptr);

  // final: y[b][co][s] = sum_ci Wo[co][ci]*ao_t[s][ci] + bo[co] + x ; M=512, N=4096, K=512
  hipLaunchKernelGGL((gemm_k<3, 128, 128>), dim3(32, 4, 4), dim3(256), 0, stream,
                     Wh + (size_t)3 * 512 * 512, 512, 0LL, aot, 512, (long long)BHW,
                     out, 4096, (long long)BHW, 512,
                     bo, x, (long long)BHW, 0.f,
                     nullptr, nullptr, nullptr, nullptr, nullptr, nullptr);
}

// Round 5
// 408.515 us; speedup vs baseline: 1.7999x; 1.0840x over previous
//
#include <hip/hip_runtime.h>

typedef _Float16 f16x8 __attribute__((ext_vector_type(8)));
typedef float f32x4 __attribute__((ext_vector_type(4)));
typedef unsigned short u16;
typedef unsigned short u16x8 __attribute__((ext_vector_type(8)));

__device__ __forceinline__ u16 f2h(float f) {
  union { _Float16 h; u16 u; } v; v.h = (_Float16)f; return v.u;
}
__device__ __forceinline__ float h2f(u16 u) {
  union { _Float16 h; u16 u; } v; v.u = u; return (float)v.h;
}

// async global -> LDS, 16 B per lane, wave-uniform LDS base (+lane*16 by HW)
__device__ __forceinline__ void gload16(const u16* g, u16* l) {
  __builtin_amdgcn_global_load_lds((const __attribute__((address_space(1))) unsigned*)g,
                                   (__attribute__((address_space(3))) unsigned*)l, 16, 0, 0);
}

// ---------------- cast 4 weight matrices (512x512 each) to fp16 ----------------
__global__ void cast4_k(const float* __restrict__ a0, const float* __restrict__ a1,
                        const float* __restrict__ a2, const float* __restrict__ a3,
                        u16* __restrict__ o) {
  const float* src = blockIdx.y == 0 ? a0 : blockIdx.y == 1 ? a1 : blockIdx.y == 2 ? a2 : a3;
  int i = blockIdx.x * 256 + threadIdx.x;
  o[(size_t)blockIdx.y * 262144 + i] = f2h(src[i]);
}

// ---------------- GroupNorm: x (b,c,hw) fp32 -> xn_t (b,hw,c) fp16 ----------------
__global__ void gn_k(const float* __restrict__ x, const float* __restrict__ g_,
                     const float* __restrict__ b_, u16* __restrict__ xnt) {
  const int g = blockIdx.x, b = blockIdx.y;
  const float* xb = x + ((size_t)b * 512 + g * 16) * 4096;
  u16* ob = xnt + (size_t)b * 4096 * 512 + g * 16;
  const float4* x4 = (const float4*)xb;
  float s = 0.f, ss = 0.f;
  for (int i = threadIdx.x; i < 16384; i += 256) {
    float4 v = x4[i];
    s += v.x + v.y + v.z + v.w;
    ss += v.x * v.x + v.y * v.y + v.z * v.z + v.w * v.w;
  }
  #pragma unroll
  for (int o = 32; o; o >>= 1) { s += __shfl_down(s, o); ss += __shfl_down(ss, o); }
  __shared__ float rs[4], rss[4];
  if ((threadIdx.x & 63) == 0) { rs[threadIdx.x >> 6] = s; rss[threadIdx.x >> 6] = ss; }
  __syncthreads();
  s = rs[0] + rs[1] + rs[2] + rs[3];
  ss = rss[0] + rss[1] + rss[2] + rss[3];
  const float mean = s * (1.f / 65536.f);
  const float rstd = rsqrtf(ss * (1.f / 65536.f) - mean * mean + 1e-6f);
  __shared__ float tile[16 * 257];
  const int cc_w = threadIdx.x & 15;
  const float gam = g_[g * 16 + cc_w] * rstd;
  const float bet = b_[g * 16 + cc_w] - mean * gam;
  for (int s0 = 0; s0 < 4096; s0 += 256) {
    __syncthreads();
    #pragma unroll
    for (int cc = 0; cc < 16; ++cc)
      tile[cc * 257 + threadIdx.x] = xb[(size_t)cc * 4096 + s0 + threadIdx.x];
    __syncthreads();
    #pragma unroll
    for (int it = 0; it < 16; ++it) {
      int sl = it * 16 + (threadIdx.x >> 4);
      float v = tile[cc_w * 257 + sl] * gam + bet;
      ob[(size_t)(s0 + sl) * 512 + cc_w] = f2h(v);
    }
  }
}

// ---------------- row softmax, in-place on S fp16; grid (4096, batch) ----------------
__global__ void softmax_k(u16* __restrict__ S) {
  const size_t ro = ((size_t)blockIdx.y * 4096 + blockIdx.x) * 4096;
  u16x8* rv = (u16x8*)(S + ro);
  const int tid = threadIdx.x;
  u16x8 h[2];
  h[0] = rv[tid];
  h[1] = rv[256 + tid];
  float v[16];
  #pragma unroll
  for (int t = 0; t < 2; ++t)
    #pragma unroll
    for (int j = 0; j < 8; ++j) v[t * 8 + j] = h2f(h[t][j]);
  float mx = -1e30f;
  #pragma unroll
  for (int i = 0; i < 16; ++i) mx = fmaxf(mx, v[i]);
  #pragma unroll
  for (int o = 32; o; o >>= 1) mx = fmaxf(mx, __shfl_down(mx, o));
  __shared__ float rm[4], rsu[4];
  if ((tid & 63) == 0) rm[tid >> 6] = mx;
  __syncthreads();
  mx = fmaxf(fmaxf(rm[0], rm[1]), fmaxf(rm[2], rm[3]));
  float sum = 0.f;
  #pragma unroll
  for (int i = 0; i < 16; ++i) { v[i] = __expf(v[i] - mx); sum += v[i]; }
  #pragma unroll
  for (int o = 32; o; o >>= 1) sum += __shfl_down(sum, o);
  if ((tid & 63) == 0) rsu[tid >> 6] = sum;
  __syncthreads();
  const float rinv = 1.f / (rsu[0] + rsu[1] + rsu[2] + rsu[3]);
  #pragma unroll
  for (int t = 0; t < 2; ++t) {
    u16x8 o8;
    #pragma unroll
    for (int j = 0; j < 8; ++j) o8[j] = f2h(v[t * 8 + j] * rinv);
    rv[t * 256 + tid] = o8;
  }
}

// ---------------- small fp16 MFMA GEMM (m97 structure), modes 4/5 ----------------
// MODE 4: C fp16 = D (m-major)                    [V' = Wo.V]
// MODE 5: QKV: z = proj*4+batch; q,k,v -> n-major fp16 +bias
template<int MODE, int BM, int BN>
__global__ void gemm_k(const u16* __restrict__ A, int lda, long long sAz,
                       const u16* __restrict__ B, int ldb, long long sBz,
                       void* __restrict__ Cp_, int ldc, long long sCz,
                       int K,
                       u16* __restrict__ Cq, u16* __restrict__ Ck, u16* __restrict__ Cvv,
                       const float* __restrict__ bq, const float* __restrict__ bk,
                       const float* __restrict__ bvp) {
  // chunked XCD swizzle (T1)
  const unsigned gx = gridDim.x, gy = gridDim.y;
  const unsigned lin = (blockIdx.z * gy + blockIdx.y) * gx + blockIdx.x;
  const unsigned nwg = gx * gy * gridDim.z;
  const unsigned swz = (lin & 7) * (nwg >> 3) + (lin >> 3);
  const unsigned bx = swz % gx;
  const unsigned rem = swz / gx;
  const unsigned by = rem % gy;
  const unsigned bz = rem / gy;

  constexpr int LK = 64;  // linear — required by global_load_lds
  __shared__ u16 As[BM * LK];
  __shared__ u16 Bs[BN * LK];
  const int tid = threadIdx.x;
  const int m0 = by * BM;
  const int n0 = bx * BN;

  const u16* Ab;
  const u16* Bb;
  if constexpr (MODE == 5) {
    int proj = bz >> 2, b = bz & 3;
    Ab = A + (size_t)proj * 512 * 512;
    Bb = B + (size_t)b * 4096 * 512;
  } else {
    Ab = A + (size_t)bz * sAz;
    Bb = B + (size_t)bz * sBz;
  }

  constexpr int FM = BM / 32, FN = BN / 32;
  f32x4 acc[FM][FN];
  #pragma unroll
  for (int i = 0; i < FM; ++i)
    #pragma unroll
    for (int j = 0; j < FN; ++j)
      acc[i][j] = (f32x4){0.f, 0.f, 0.f, 0.f};

  const int wid = tid >> 6;
  const int lane = tid & 63;
  const int wm = (wid >> 1) * (BM / 2);
  const int wn = (wid & 1) * (BN / 2);
  const int l15 = lane & 15;
  const int lk8 = (lane >> 4) * 8;
  const int lrow = lane >> 3;
  const int lcol = (lane & 7) * 8;

  constexpr int ACH = BM / 8;
  constexpr int BCH = BN / 8;

  for (int k0 = 0; k0 < K; k0 += 64) {
    #pragma unroll
    for (int c = 0; c < ACH / 4; ++c) {
      int ch = wid * (ACH / 4) + c;
      gload16(Ab + (size_t)(m0 + ch * 8 + lrow) * lda + k0 + lcol, &As[ch * 512]);
    }
    #pragma unroll
    for (int c = 0; c < BCH / 4; ++c) {
      int ch = wid * (BCH / 4) + c;
      gload16(Bb + (size_t)(n0 + ch * 8 + lrow) * ldb + k0 + lcol, &Bs[ch * 512]);
    }
    __syncthreads();
    #pragma unroll
    for (int kk = 0; kk < 64; kk += 32) {
      f16x8 af[FM], bfr[FN];
      #pragma unroll
      for (int i = 0; i < FM; ++i)
        af[i] = *(const f16x8*)&As[(wm + i * 16 + l15) * LK + kk + lk8];
      #pragma unroll
      for (int j = 0; j < FN; ++j)
        bfr[j] = *(const f16x8*)&Bs[(wn + j * 16 + l15) * LK + kk + lk8];
      #pragma unroll
      for (int i = 0; i < FM; ++i)
        #pragma unroll
        for (int j = 0; j < FN; ++j)
          acc[i][j] = __builtin_amdgcn_mfma_f32_16x16x32_f16(af[i], bfr[j], acc[i][j], 0, 0, 0);
    }
    __syncthreads();
  }

  const int lq4 = (lane >> 4) * 4;
  if constexpr (MODE == 5) {
    int proj = bz >> 2, b = bz & 3;
    const float* bs = proj == 0 ? bq : (proj == 1 ? bk : bvp);
    u16* C = (proj == 0 ? Cq : (proj == 1 ? Ck : Cvv)) + (size_t)b * 4096 * 512;
    #pragma unroll
    for (int i = 0; i < FM; ++i) {
      int mb = m0 + wm + i * 16 + lq4;
      float b0 = bs[mb], b1 = bs[mb + 1], b2 = bs[mb + 2], b3 = bs[mb + 3];
      #pragma unroll
      for (int j = 0; j < FN; ++j) {
        int n = n0 + wn + j * 16 + l15;
        ushort4 o4;
        o4.x = f2h(acc[i][j][0] + b0); o4.y = f2h(acc[i][j][1] + b1);
        o4.z = f2h(acc[i][j][2] + b2); o4.w = f2h(acc[i][j][3] + b3);
        *(ushort4*)(C + (size_t)n * 512 + mb) = o4;  // n-major
      }
    }
    return;
  }
  // MODE 4: fp16 m-major
  u16* C = (u16*)Cp_ + (size_t)bz * sCz;
  #pragma unroll
  for (int i = 0; i < FM; ++i) {
    int mb = m0 + wm + i * 16 + lq4;
    #pragma unroll
    for (int j = 0; j < FN; ++j) {
      int n = n0 + wn + j * 16 + l15;
      #pragma unroll
      for (int r = 0; r < 4; ++r)
        C[(size_t)(mb + r) * ldc + n] = f2h(acc[i][j][r]);
    }
  }
}

// ---------------- pipelined big GEMM: counted vmcnt + T2 swizzle + T5 setprio ----------------
// 512 threads = 8 waves (2M x 4N). BK=64, LDS double-buffered.
// EPI 0: C fp16 = D*scale (m-major)   [scores]
// EPI 1: C fp32 = D + bias[m] + resid (m-major)   [out = V'.P^T + bo + x]
template<int BM, int BN, int EPI>
__global__ __launch_bounds__(512, 2)
void gemm8_k(const u16* __restrict__ A, int lda, long long sAz,
             const u16* __restrict__ B, int ldb, long long sBz,
             void* __restrict__ Cp_, int ldc, long long sCz,
             int K,
             const float* __restrict__ bias,
             const float* __restrict__ resid, long long sRz,
             float scale) {
  // chunked XCD swizzle (T1); all grids are %8==0
  const unsigned gx = gridDim.x, gy = gridDim.y;
  const unsigned lin = (blockIdx.z * gy + blockIdx.y) * gx + blockIdx.x;
  const unsigned nwg = gx * gy * gridDim.z;
  const unsigned swzb = (lin & 7) * (nwg >> 3) + (lin >> 3);
  const unsigned bx = swzb % gx;
  const unsigned rem = swzb / gx;
  const unsigned by = rem % gy;
  const unsigned bz = rem / gy;

  constexpr int ACH = BM / 64;        // gload16 issues per thread for A per K-tile
  constexpr int BCH = BN / 64;
  constexpr int NLD = ACH + BCH;      // loads in flight per staged K-tile
  constexpr int HBUF = (BM + BN) * 64;  // u16 per buffer
  __shared__ u16 lds[2 * HBUF];

  const int tid = threadIdx.x;
  const int m0 = by * BM;
  const int n0 = bx * BN;
  const u16* Ab = A + (size_t)bz * sAz + (size_t)m0 * lda;
  const u16* Bb = B + (size_t)bz * sBz + (size_t)n0 * ldb;

  // per-thread staging offsets (inverse-swizzled global source, linear LDS dest)
  int offA[ACH], offB[BCH];
  #pragma unroll
  for (int i = 0; i < ACH; ++i) {
    int ch = i * 512 + tid;
    int row = ch >> 3;
    int c16 = (ch & 7) ^ (row & 7);
    offA[i] = row * lda + c16 * 8;
  }
  #pragma unroll
  for (int i = 0; i < BCH; ++i) {
    int ch = i * 512 + tid;
    int row = ch >> 3;
    int c16 = (ch & 7) ^ (row & 7);
    offB[i] = row * ldb + c16 * 8;
  }

  const int wid = tid >> 6;
  const int lane = tid & 63;
  const int wm = (wid >> 2) * (BM / 2);   // 2 M-wave-rows
  const int wn = (wid & 3) * (BN / 4);    // 4 N-wave-cols
  const int l15 = lane & 15;
  const int lk8 = (lane >> 4) * 8;

  constexpr int FM = BM / 32;   // m-frags per wave
  constexpr int FN = BN / 64;   // n-frags per wave
  f32x4 acc[FM][FN];
  #pragma unroll
  for (int i = 0; i < FM; ++i)
    #pragma unroll
    for (int j = 0; j < FN; ++j)
      acc[i][j] = (f32x4){0.f, 0.f, 0.f, 0.f};

  const int NT = K >> 6;

  auto stage = [&](int t) {
    u16* dst = &lds[(t & 1) * HBUF];
    const u16* as = Ab + t * 64;
    #pragma unroll
    for (int i = 0; i < ACH; ++i)
      gload16(as + offA[i], dst + (i * 512 + tid) * 8);
    const u16* bs = Bb + t * 64;
    u16* dstB = dst + BM * 64;
    #pragma unroll
    for (int i = 0; i < BCH; ++i)
      gload16(bs + offB[i], dstB + (i * 512 + tid) * 8);
  };

  stage(0);
  stage(1);

  for (int t = 0; t < NT; ++t) {
    // wait own tile-t chunks (t+1's NLD may stay in flight), then block-wide agree
    if (t < NT - 1)
      asm volatile("s_waitcnt vmcnt(%0)" :: "i"(NLD) : "memory");
    else
      asm volatile("s_waitcnt vmcnt(0)" ::: "memory");
    __builtin_amdgcn_s_barrier();
    __builtin_amdgcn_sched_barrier(0);

    const u16* Asp = &lds[(t & 1) * HBUF];
    const u16* Bsp = Asp + BM * 64;

    // all B-frags for this K-tile (swizzled read)
    f16x8 bf[2][FN];
    #pragma unroll
    for (int k2 = 0; k2 < 2; ++k2)
      #pragma unroll
      for (int j = 0; j < FN; ++j) {
        int row = wn + j * 16 + l15;
        int col = (k2 * 32 + lk8) ^ ((row & 7) << 3);
        bf[k2][j] = *(const f16x8*)&Bsp[row * 64 + col];
      }
    // quadrant phases: 2 m-frags x FN x 2kk MFMA each, no intra-tile barriers
    #pragma unroll
    for (int q = 0; q < FM / 2; ++q) {
      f16x8 af[2][2];
      #pragma unroll
      for (int k2 = 0; k2 < 2; ++k2)
        #pragma unroll
        for (int s = 0; s < 2; ++s) {
          int row = wm + (2 * q + s) * 16 + l15;
          int col = (k2 * 32 + lk8) ^ ((row & 7) << 3);
          af[k2][s] = *(const f16x8*)&Asp[row * 64 + col];
        }
      __builtin_amdgcn_s_setprio(1);
      #pragma unroll
      for (int k2 = 0; k2 < 2; ++k2)
        #pragma unroll
        for (int s = 0; s < 2; ++s)
          #pragma unroll
          for (int j = 0; j < FN; ++j)
            acc[2 * q + s][j] =
                __builtin_amdgcn_mfma_f32_16x16x32_f16(af[k2][s], bf[k2][j], acc[2 * q + s][j], 0, 0, 0);
      __builtin_amdgcn_s_setprio(0);
    }

    // all ds_reads retired before allowing next-stage LDS overwrites
    asm volatile("s_waitcnt lgkmcnt(0)" ::: "memory");
    __builtin_amdgcn_sched_barrier(0);
    __builtin_amdgcn_s_barrier();
    if (t + 2 < NT) stage(t + 2);
  }

  const int lq4 = (lane >> 4) * 4;
  #pragma unroll
  for (int i = 0; i < FM; ++i) {
    int mb = m0 + wm + i * 16 + lq4;
    #pragma unroll
    for (int j = 0; j < FN; ++j) {
      int n = n0 + wn + j * 16 + l15;
      if constexpr (EPI == 0) {
        u16* C = (u16*)Cp_ + (size_t)bz * sCz;
        #pragma unroll
        for (int r = 0; r < 4; ++r)
          C[(size_t)(mb + r) * ldc + n] = f2h(acc[i][j][r] * scale);
      } else {
        float* C = (float*)Cp_ + (size_t)bz * sCz;
        const float* R = resid + (size_t)bz * sRz;
        #pragma unroll
        for (int r = 0; r < 4; ++r)
          C[(size_t)(mb + r) * ldc + n] = acc[i][j][r] + bias[mb + r] + R[(size_t)(mb + r) * ldc + n];
      }
    }
  }
}

extern "C" void kernel_launch(void* const* d_in, const int* in_sizes, int n_in,
                              void* d_out, int out_size, void* d_ws, size_t ws_size,
                              hipStream_t stream) {
  const float* x     = (const float*)d_in[0];
  const float* gamma = (const float*)d_in[1];
  const float* beta  = (const float*)d_in[2];
  const float* wq    = (const float*)d_in[3];
  const float* bq    = (const float*)d_in[4];
  const float* wk    = (const float*)d_in[5];
  const float* bk    = (const float*)d_in[6];
  const float* wv    = (const float*)d_in[7];
  const float* bv    = (const float*)d_in[8];
  const float* wo    = (const float*)d_in[9];
  const float* bo    = (const float*)d_in[10];
  float* out = (float*)d_out;

  const size_t BHW = (size_t)4096 * 512;       // elems per batch per tensor
  const long long SS = 16777216LL;             // 4096*4096
  u16* Wh  = (u16*)d_ws;                       // 4 x 512x512 fp16 (q,k,v,o)
  u16* xnt = Wh + (size_t)4 * 512 * 512;       // (b, s, c) — reused as V' later
  u16* qt  = xnt + 4 * BHW;                    // (b, s, c)
  u16* kt  = qt + 4 * BHW;                     // (b, s, c)
  u16* vt  = kt + 4 * BHW;                     // (b, s, c)  (v now n-major too)
  u16* Sb  = vt + 4 * BHW;                     // (b, 4096, 4096) fp16, softmaxed in-place
  u16* Vp  = xnt;                              // V' = Wo.V  (b, c, s) — alias, xnt dead after QKV

  const float scale = 0.044194173824159216f;   // 512^-0.5

  hipLaunchKernelGGL(cast4_k, dim3(1024, 4), dim3(256), 0, stream, wq, wk, wv, wo, Wh);
  hipLaunchKernelGGL(gn_k, dim3(32, 4), dim3(256), 0, stream, x, gamma, beta, xnt);

  // QKV: M=512 (c_out), N=4096 (s), K=512; z = proj*4 + batch; all n-major out
  hipLaunchKernelGGL((gemm_k<5, 128, 128>), dim3(32, 4, 12), dim3(256), 0, stream,
                     Wh, 512, 0LL, xnt, 512, 0LL, nullptr, 0, 0LL, 512,
                     qt, kt, vt, bq, bk, bv);

  // S[b][i][j] = q_t[i][:].k_t[j][:] * scale ; M=N=4096, K=512
  hipLaunchKernelGGL((gemm8_k<256, 256, 0>), dim3(16, 16, 4), dim3(512), 0, stream,
                     qt, 512, (long long)BHW, kt, 512, (long long)BHW,
                     Sb, 4096, SS, 512, nullptr, nullptr, 0LL, scale);

  hipLaunchKernelGGL(softmax_k, dim3(4096, 4), dim3(256), 0, stream, Sb);

  // V'[b][co][j] = Wo[co][:].v_t[j][:] ; M=512, N=4096, K=512 (fuses final proj)
  hipLaunchKernelGGL((gemm_k<4, 128, 128>), dim3(32, 4, 4), dim3(256), 0, stream,
                     Wh + (size_t)3 * 512 * 512, 512, 0LL, vt, 512, (long long)BHW,
                     Vp, 4096, (long long)(512 * 4096), 512,
                     nullptr, nullptr, nullptr, nullptr, nullptr, nullptr);

  // out[b][co][i] = V'[co][:].P[i][:] + bo[co] + x ; M=512, N=4096, K=4096
  hipLaunchKernelGGL((gemm8_k<128, 256, 1>), dim3(16, 4, 4), dim3(512), 0, stream,
                     Vp, 4096, (long long)(512 * 4096), Sb, 4096, SS,
                     out, 4096, (long long)BHW, 4096, bo, x, (long long)BHW, 0.f);
}